// Round 11
// baseline (327.454 us; speedup 1.0000x reference)
//
#include <hip/hip_runtime.h>
#include <hip/hip_bf16.h>

#define N_NODES 20000
#define N_REL 32
#define HID 128
#define EMB 16
#define N_EDGES 600000
#define NB (N_NODES * N_REL)   // 640000 bins

typedef __attribute__((ext_vector_type(8))) short  bf8v;   // 8 bf16 (MFMA A/B frag)
typedef __attribute__((ext_vector_type(8))) unsigned short us8v; // 16-byte unit
typedef __attribute__((ext_vector_type(4))) unsigned short us4v; // 8-byte unit
typedef __attribute__((ext_vector_type(4))) float  f4v;    // MFMA C/D frag

__device__ __forceinline__ unsigned short f2b(float f) {
    __hip_bfloat16 h = __float2bfloat16(f);
    return __builtin_bit_cast(unsigned short, h);
}
__device__ __forceinline__ float b2f(unsigned short u) {
    unsigned int x = ((unsigned int)u) << 16;
    return __builtin_bit_cast(float, x);
}

// ======== pre-pass: histogram + all bf16 conversions/transposes ========
#define R_W2 (N_REL * HID * HID)        // 1048576
#define R_XB (N_NODES * 32)             // 640000
#define R_W1 (N_REL * HID * 32)         // 131072
#define R_R1 (HID * 32)                 // 4096
#define R_R2 (HID * HID)                // 16384
#define R_HIST N_EDGES                  // 600000
#define PRE_TOT (R_W2 + R_XB + R_W1 + R_R1 + R_R2 + R_HIST)

__global__ __launch_bounds__(256) void pre1_k(
    const int* __restrict__ dst, const int* __restrict__ et,
    const float* __restrict__ x, const float* __restrict__ W1,
    const float* __restrict__ root1, const float* __restrict__ W2,
    const float* __restrict__ root2,
    int* __restrict__ hist,
    unsigned short* __restrict__ xb, unsigned short* __restrict__ w1t,
    unsigned short* __restrict__ r1t, unsigned short* __restrict__ w2t,
    unsigned short* __restrict__ r2t) {
    int i = blockIdx.x * 256 + threadIdx.x;
    if (i < R_W2) {
        int r = i >> 14, k = (i >> 7) & 127, n = i & 127;
        w2t[(r << 14) + (n << 7) + k] = f2b(W2[i]);
        return;
    }
    i -= R_W2;
    if (i < R_XB) {
        int n = i >> 5, k = i & 31;
        xb[i] = (k < EMB) ? f2b(x[n * EMB + k]) : (unsigned short)0;
        return;
    }
    i -= R_XB;
    if (i < R_W1) {
        int r = i >> 12, n = (i >> 5) & 127, k = i & 31;
        w1t[i] = (k < EMB) ? f2b(W1[(r << 11) + (k << 7) + n]) : (unsigned short)0;
        return;
    }
    i -= R_W1;
    if (i < R_R1) {
        int n = i >> 5, k = i & 31;
        r1t[i] = (k < EMB) ? f2b(root1[(k << 7) + n]) : (unsigned short)0;
        return;
    }
    i -= R_R1;
    if (i < R_R2) {
        int n = i >> 7, k = i & 127;
        r2t[i] = f2b(root2[(k << 7) + n]);
        return;
    }
    i -= R_R2;
    if (i < R_HIST) atomicAdd(&hist[dst[i] * N_REL + et[i]], 1);
}

// ======== 2-level exclusive scan over NB = 625 x 1024 (+ inv fused) ========
__global__ void scan1_k(const int* __restrict__ hist, int* __restrict__ binoff,
                        int* __restrict__ bsum, float* __restrict__ inv) {
    __shared__ int sh[256];
    const int t = threadIdx.x;
    const int base = blockIdx.x * 1024 + t * 4;
    int4 h4 = *(const int4*)(hist + base);
    float4 iv4;
    iv4.x = h4.x > 0 ? 1.0f / h4.x : 0.0f;
    iv4.y = h4.y > 0 ? 1.0f / h4.y : 0.0f;
    iv4.z = h4.z > 0 ? 1.0f / h4.z : 0.0f;
    iv4.w = h4.w > 0 ? 1.0f / h4.w : 0.0f;
    *(float4*)(inv + base) = iv4;
    int ts = h4.x + h4.y + h4.z + h4.w;
    sh[t] = ts;
    __syncthreads();
    for (int o = 1; o < 256; o <<= 1) {
        int v = (t >= o) ? sh[t - o] : 0;
        __syncthreads();
        sh[t] += v;
        __syncthreads();
    }
    int exc = sh[t] - ts;
    binoff[base + 0] = exc;
    binoff[base + 1] = exc + h4.x;
    binoff[base + 2] = exc + h4.x + h4.y;
    binoff[base + 3] = exc + h4.x + h4.y + h4.z;
    if (t == 255) bsum[blockIdx.x] = sh[255];
}

__global__ void scan2_k(const int* __restrict__ bsum, int* __restrict__ bbase) {
    __shared__ int sh[1024];
    const int t = threadIdx.x;
    int v = (t < 625) ? bsum[t] : 0;
    sh[t] = v;
    __syncthreads();
    for (int o = 1; o < 1024; o <<= 1) {
        int u = (t >= o) ? sh[t - o] : 0;
        __syncthreads();
        sh[t] += u;
        __syncthreads();
    }
    if (t < 625) bbase[t] = sh[t] - v;
}

__global__ void scan3_k(int* __restrict__ binoff, const int* __restrict__ bbase,
                        int* __restrict__ cursors) {
    int i = blockIdx.x * 256 + threadIdx.x;
    if (i < NB) {
        int v = binoff[i] + bbase[i >> 10];
        binoff[i] = v;
        cursors[i] = v;
    }
    if (i == 0) binoff[NB] = N_EDGES;
}

__global__ void scatter_k(const int* __restrict__ src, const int* __restrict__ dst,
                          const int* __restrict__ et, int* __restrict__ cursors,
                          int* __restrict__ ssrc) {
    int e = blockIdx.x * 256 + threadIdx.x;
    if (e < N_EDGES) {
        int b = dst[e] * N_REL + et[e];
        int p = atomicAdd(&cursors[b], 1);
        ssrc[p] = src[e];
    }
}

// ======== fused aggregate+transform, relation-split, fp32 partials ========
// grid (625, N_REL/RG). Block y handles relations [y*RG, y*RG+RG); last group
// also adds the root transform. Output: 32x128 fp32 partial at part+y*N*HID.
// Meta preloaded to LDS. G-load pipeline is 2 ITERATIONS deep: at iter `it`
// (post-barrier) G-rows for it+2 are issued (srcs prefetched at it-1), giving
// each load ~2 full iterations to complete before consumption.
template<int KT, int LSS, int CW, int RG>
__global__ __launch_bounds__(256) void gemm_f(
    const int* __restrict__ binoff, const float* __restrict__ inv,
    const int* __restrict__ ssrc,
    const unsigned short* __restrict__ G,    // bf16 rows [*, KT*32]
    const unsigned short* __restrict__ Bw,   // bf16 W^T [r][128][KT*32]
    const unsigned short* __restrict__ Br,   // bf16 root^T [128][KT*32]
    float* __restrict__ part) {

    constexpr int ROW = KT * 32;
    constexpr int NCH = ROW / CW;
    constexpr int CP8 = CW / 8;
    static_assert(NCH * CW == ROW, "chunk covering must be exact");
    static_assert(32 * NCH <= 256, "one gather item per thread");

    __shared__ __align__(16) unsigned short As[2][32 * LSS];
    __shared__ int   smO[32 * (RG + 1)];
    __shared__ float smI[32 * RG];

    const int t = threadIdx.x;
    const int w = t >> 6, lane = t & 63;
    const int q = lane >> 4, m16 = lane & 15;
    const int d0 = blockIdx.x * 32;
    const int r0 = blockIdx.y * RG;
    const bool isLast = (blockIdx.y == gridDim.y - 1);
    const int colb = w * 32;
    const bool gat = t < 32 * NCH;
    const int grow = t / NCH, gcc = t % NCH;
    const int mb  = grow * (RG + 1);
    const int mbI = grow * RG;

    // ---- meta preload (this group's bins only) ----
    for (int i = t; i < 32 * (RG + 1); i += 256) {
        int row = i / (RG + 1), rr = i % (RG + 1);
        smO[i] = binoff[(d0 + row) * N_REL + r0 + rr];
    }
    for (int i = t; i < 32 * RG; i += 256) {
        int row = i / RG, rr = i % RG;
        smI[i] = inv[(d0 + row) * N_REL + r0 + rr];
    }
    __syncthreads();

    f4v acc[2][2];
#pragma unroll
    for (int rt = 0; rt < 2; ++rt)
#pragma unroll
        for (int ct = 0; ct < 2; ++ct) acc[rt][ct] = f4v{0.f, 0.f, 0.f, 0.f};

    // ---- prologue: prime 2-stage G pipeline (stages for it=0, it=1) ----
    us8v gA[2][CP8], gB[2][CP8];
#pragma unroll
    for (int s = 0; s < 2; ++s)
#pragma unroll
        for (int j = 0; j < CP8; ++j) { gA[s][j] = us8v{}; gB[s][j] = us8v{}; }
    int sxh = 0, syh = 0;   // srcs held for the NEXT stage to issue (it+2)
    if (gat) {
#pragma unroll
        for (int s = 0; s < 2 && s < RG; ++s) {
            int so = smO[mb + s], c = smO[mb + s + 1] - so;
            if (c >= 1) {
                const unsigned short* gp = G + (size_t)ssrc[so] * ROW + gcc * CW;
#pragma unroll
                for (int j = 0; j < CP8; ++j) gA[s][j] = *(const us8v*)(gp + j * 8);
            }
            if (c >= 2) {
                const unsigned short* gp = G + (size_t)ssrc[so + 1] * ROW + gcc * CW;
#pragma unroll
                for (int j = 0; j < CP8; ++j) gB[s][j] = *(const us8v*)(gp + j * 8);
            }
        }
        if (RG > 2) {
            int so = smO[mb + 2], c = smO[mb + 3] - so;
            if (c >= 1) sxh = ssrc[so];
            if (c >= 2) syh = ssrc[so + 1];
        }
    }

    // B fragments for it=0
    bf8v bfr[2][KT];
#pragma unroll
    for (int ct = 0; ct < 2; ++ct) {
        const int n = colb + 16 * ct + m16;
#pragma unroll
        for (int ks = 0; ks < KT; ++ks)
            bfr[ct][ks] = *(const bf8v*)(Bw + ((size_t)r0 * HID + n) * ROW + ks * 32 + q * 8);
    }

#pragma unroll
    for (int it = 0; it < RG; ++it) {
        const int st = it & 1;
        unsigned short* Ab = As[st];
        // ---- gather (consumes pipeline stage st) ----
        if (gat) {
            const int so = smO[mb + it], eo = smO[mb + it + 1];
            const int cnt = eo - so;
            float a[CW];
#pragma unroll
            for (int j = 0; j < CW; ++j) a[j] = 0.f;
            if (cnt >= 1) {
#pragma unroll
                for (int j = 0; j < CP8; ++j)
#pragma unroll
                    for (int k = 0; k < 8; ++k) a[j * 8 + k] += b2f(gA[st][j][k]);
            }
            if (cnt >= 2) {
#pragma unroll
                for (int j = 0; j < CP8; ++j)
#pragma unroll
                    for (int k = 0; k < 8; ++k) a[j * 8 + k] += b2f(gB[st][j][k]);
            }
            for (int p = so + 2; p < eo; ++p) {     // rare tail
                const unsigned short* gp = G + (size_t)ssrc[p] * ROW + gcc * CW;
#pragma unroll
                for (int j = 0; j < CP8; ++j) {
                    us8v g = *(const us8v*)(gp + j * 8);
#pragma unroll
                    for (int k = 0; k < 8; ++k) a[j * 8 + k] += b2f(g[k]);
                }
            }
            const float iv = smI[mbI + it];
            unsigned short* wp = &Ab[grow * LSS + gcc * CW];
#pragma unroll
            for (int j = 0; j < CP8; ++j) {
                us8v sv;
#pragma unroll
                for (int k = 0; k < 8; ++k) sv[k] = f2b(a[j * 8 + k] * iv);
                *(us8v*)(wp + j * 8) = sv;
            }
        }
        __syncthreads();

        // ---- issue G(it+2) into the just-freed stage; fetch srcs for it+3 ----
        if (gat && it + 2 < RG) {
            const int c2 = smO[mb + it + 3] - smO[mb + it + 2];
            if (c2 >= 1) {
                const unsigned short* gp = G + (size_t)sxh * ROW + gcc * CW;
#pragma unroll
                for (int j = 0; j < CP8; ++j) gA[st][j] = *(const us8v*)(gp + j * 8);
            }
            if (c2 >= 2) {
                const unsigned short* gp = G + (size_t)syh * ROW + gcc * CW;
#pragma unroll
                for (int j = 0; j < CP8; ++j) gB[st][j] = *(const us8v*)(gp + j * 8);
            }
            if (it + 3 < RG) {
                const int so3 = smO[mb + it + 3], c3 = smO[mb + it + 4] - so3;
                if (c3 >= 1) sxh = ssrc[so3];
                if (c3 >= 2) syh = ssrc[so3 + 1];
            }
        }

        // ---- A fragments + MFMA ----
#pragma unroll
        for (int rt = 0; rt < 2; ++rt) {
            const unsigned short* ar = &Ab[(m16 + 16 * rt) * LSS];
#pragma unroll
            for (int ks = 0; ks < KT; ++ks) {
                bf8v af = *(const bf8v*)(ar + ks * 32 + q * 8);
                acc[rt][0] = __builtin_amdgcn_mfma_f32_16x16x32_bf16(af, bfr[0][ks], acc[rt][0], 0, 0, 0);
                acc[rt][1] = __builtin_amdgcn_mfma_f32_16x16x32_bf16(af, bfr[1][ks], acc[rt][1], 0, 0, 0);
            }
        }

        // ---- B fragments for it+1 (root weights after last relation of last group) ----
        const unsigned short* Bp = (it + 1 < RG) ? (Bw + (size_t)(r0 + it + 1) * HID * ROW)
                                                 : (isLast ? Br : nullptr);
        if (Bp) {
#pragma unroll
            for (int ct = 0; ct < 2; ++ct) {
                const int n = colb + 16 * ct + m16;
#pragma unroll
                for (int ks = 0; ks < KT; ++ks)
                    bfr[ct][ks] = *(const bf8v*)(Bp + (size_t)n * ROW + ks * 32 + q * 8);
            }
        }
    }

    // ---- root transform (last group only): A straight from global ----
    if (isLast) {
#pragma unroll
        for (int rt = 0; rt < 2; ++rt) {
#pragma unroll
            for (int ks = 0; ks < KT; ++ks) {
                bf8v af = *(const bf8v*)(G + (size_t)(d0 + m16 + 16 * rt) * ROW + ks * 32 + q * 8);
                acc[rt][0] = __builtin_amdgcn_mfma_f32_16x16x32_bf16(af, bfr[0][ks], acc[rt][0], 0, 0, 0);
                acc[rt][1] = __builtin_amdgcn_mfma_f32_16x16x32_bf16(af, bfr[1][ks], acc[rt][1], 0, 0, 0);
            }
        }
    }

    // ---- epilogue: direct fp32 partial stores ----
    float* pb = part + (size_t)blockIdx.y * N_NODES * HID;
#pragma unroll
    for (int ct = 0; ct < 2; ++ct) {
        const int col = colb + 16 * ct + m16;
#pragma unroll
        for (int rt = 0; rt < 2; ++rt) {
#pragma unroll
            for (int g = 0; g < 4; ++g) {
                const int rr = 16 * rt + q * 4 + g;
                pb[(size_t)(d0 + rr) * HID + col] = acc[rt][ct][g];
            }
        }
    }
}

// ======== reduces ========
__global__ __launch_bounds__(256) void reduce1_k(
    const float* __restrict__ part, const float* __restrict__ b1,
    unsigned short* __restrict__ h1b) {
    int i = blockIdx.x * 256 + threadIdx.x;   // float4 index
    if (i >= N_NODES * HID / 4) return;
    const size_t S = (size_t)N_NODES * HID;
    float4 a0 = ((const float4*)part)[i];
    float4 a1 = ((const float4*)(part + S))[i];
    float4 a2 = ((const float4*)(part + 2 * S))[i];
    float4 a3 = ((const float4*)(part + 3 * S))[i];
    float4 bb = *(const float4*)(b1 + ((i * 4) & 127));
    us4v v;
    v[0] = f2b(fmaxf((a0.x + a1.x) + (a2.x + a3.x) + bb.x, 0.0f));
    v[1] = f2b(fmaxf((a0.y + a1.y) + (a2.y + a3.y) + bb.y, 0.0f));
    v[2] = f2b(fmaxf((a0.z + a1.z) + (a2.z + a3.z) + bb.z, 0.0f));
    v[3] = f2b(fmaxf((a0.w + a1.w) + (a2.w + a3.w) + bb.w, 0.0f));
    *(us4v*)(h1b + (size_t)i * 4) = v;
}

__global__ __launch_bounds__(256) void reduce2_k(
    const float* __restrict__ part, const float* __restrict__ b2,
    float* __restrict__ out) {
    int i = blockIdx.x * 256 + threadIdx.x;   // float4 index
    if (i >= N_NODES * HID / 4) return;
    const size_t S = (size_t)N_NODES * HID;
    float4 r = *(const float4*)(b2 + ((i * 4) & 127));
#pragma unroll
    for (int p = 0; p < 8; ++p) {
        float4 a = ((const float4*)(part + p * S))[i];
        r.x += a.x; r.y += a.y; r.z += a.z; r.w += a.w;
    }
    ((float4*)out)[i] = r;
}

extern "C" void kernel_launch(void* const* d_in, const int* in_sizes, int n_in,
                              void* d_out, int out_size, void* d_ws, size_t ws_size,
                              hipStream_t stream) {
    const int*   ei    = (const int*)d_in[0];   // [2, E]
    const int*   et    = (const int*)d_in[1];   // [E]
    const float* x     = (const float*)d_in[2]; // [N, 16]
    const float* W1    = (const float*)d_in[3]; // [32, 16, 128]
    const float* root1 = (const float*)d_in[4]; // [16, 128]
    const float* b1    = (const float*)d_in[5]; // [128]
    const float* W2    = (const float*)d_in[6]; // [32, 128, 128]
    const float* root2 = (const float*)d_in[7]; // [128, 128]
    const float* b2    = (const float*)d_in[8]; // [128]
    float* out = (float*)d_out;

    // ---- workspace layout (~100 MB) ----
    char* ws = (char*)d_ws;
    size_t off = 0;
    auto alloc = [&](size_t bytes) { void* p = ws + off; off = (off + bytes + 63) & ~(size_t)63; return p; };
    int*   hist    = (int*)  alloc((size_t)NB * 4);
    int*   binoff  = (int*)  alloc((size_t)(NB + 1) * 4);
    int*   cursors = (int*)  alloc((size_t)NB * 4);
    float* inv     = (float*)alloc((size_t)NB * 4);
    int*   bsum    = (int*)  alloc(625 * 4);
    int*   bbase   = (int*)  alloc(625 * 4);
    int*   ssrc    = (int*)  alloc((size_t)(N_EDGES + 2) * 4);
    unsigned short* xb  = (unsigned short*)alloc((size_t)N_NODES * 32 * 2);
    unsigned short* h1b = (unsigned short*)alloc((size_t)N_NODES * HID * 2);
    unsigned short* w1t = (unsigned short*)alloc((size_t)N_REL * HID * 32 * 2);
    unsigned short* r1t = (unsigned short*)alloc((size_t)HID * 32 * 2);
    unsigned short* w2t = (unsigned short*)alloc((size_t)N_REL * HID * HID * 2);
    unsigned short* r2t = (unsigned short*)alloc((size_t)HID * HID * 2);
    float* part = (float*)alloc((size_t)8 * N_NODES * HID * 4);   // 8 partials, reused both layers

    const int* src = ei;
    const int* dst = ei + N_EDGES;

    hipMemsetAsync(hist, 0, (size_t)NB * 4, stream);
    pre1_k<<<(PRE_TOT + 255) / 256, 256, 0, stream>>>(
        dst, et, x, W1, root1, W2, root2, hist, xb, w1t, r1t, w2t, r2t);
    scan1_k<<<NB / 1024, 256, 0, stream>>>(hist, binoff, bsum, inv);
    scan2_k<<<1, 1024, 0, stream>>>(bsum, bbase);
    scan3_k<<<(NB + 255) / 256, 256, 0, stream>>>(binoff, bbase, cursors);
    scatter_k<<<(N_EDGES + 255) / 256, 256, 0, stream>>>(src, dst, et, cursors, ssrc);

    // ---- layer 1: 4 relation groups (8 rels each; last adds root) ----
    gemm_f<1, 40, 8, 8><<<dim3(625, 4), 256, 0, stream>>>(
        binoff, inv, ssrc, xb, w1t, r1t, part);
    reduce1_k<<<(N_NODES * HID / 4 + 255) / 256, 256, 0, stream>>>(part, b1, h1b);

    // ---- layer 2: 8 relation groups (4 rels each; last adds root) ----
    gemm_f<4, 136, 16, 4><<<dim3(625, 8), 256, 0, stream>>>(
        binoff, inv, ssrc, h1b, w2t, r2t, part);
    reduce2_k<<<(N_NODES * HID / 4 + 255) / 256, 256, 0, stream>>>(part, b2, out);
}